// Round 5
// baseline (784.309 us; speedup 1.0000x reference)
//
#include <hip/hip_runtime.h>

#define D 128

typedef __attribute__((ext_vector_type(2))) float f32x2;
typedef __attribute__((ext_vector_type(4))) float f32x4;
typedef __attribute__((ext_vector_type(16))) float f32x16;
typedef __attribute__((ext_vector_type(8))) _Float16 f16x8;
typedef __attribute__((ext_vector_type(2))) __fp16 fp16v2;
typedef __attribute__((ext_vector_type(4))) unsigned int u32x4;

// split f32 pair -> packed f16 hi-pair + lo-pair
__device__ __forceinline__ void split2(float a, float b, unsigned &hi, unsigned &lo) {
  fp16v2 h = __builtin_amdgcn_cvt_pkrtz(a, b);
  float ra = a - (float)h[0];
  float rb = b - (float)h[1];
  fp16v2 lv = __builtin_amdgcn_cvt_pkrtz(ra, rb);
  hi = __builtin_bit_cast(unsigned, h);
  lo = __builtin_bit_cast(unsigned, lv);
}

__device__ __forceinline__ f32x16 mm(u32x4 a, u32x4 b, f32x16 c) {
  return __builtin_amdgcn_mfma_f32_32x32x16_f16(
      __builtin_bit_cast(f16x8, a), __builtin_bit_cast(f16x8, b), c, 0, 0, 0);
}

__device__ __forceinline__ f32x16 zero16() {
  f32x16 z;
#pragma unroll
  for (int e = 0; e < 16; ++e) z[e] = 0.f;
  return z;
}

// ---------------------------------------------------------------------------
// Kernel 1: W = 0.95 I - A^T A + B - B^T ;  Mm = 2 I - W
// ---------------------------------------------------------------------------
__global__ void wmat_kernel(const float* __restrict__ A, const float* __restrict__ B,
                            float* __restrict__ W, float* __restrict__ Mm) {
  const int i = blockIdx.x;
  const int j = threadIdx.x;
  float s = 0.f;
#pragma unroll 8
  for (int k = 0; k < D; ++k) s = fmaf(A[k * D + i], A[k * D + j], s);
  const float diag = (i == j) ? 1.f : 0.f;
  const float w = 0.95f * diag - s + B[i * D + j] - B[j * D + i];
  W[i * D + j] = w;
  Mm[i * D + j] = 2.f * diag - w;
}

// ---------------------------------------------------------------------------
// Kernel 2: Winv = Mm^{-1}, register-resident Gauss-Jordan (no pivoting).
// ---------------------------------------------------------------------------
__global__ __launch_bounds__(1024) void inv_kernel(const float* __restrict__ Mm,
                                                   float* __restrict__ Winv) {
  __shared__ float rowbuf[2 * D];
  __shared__ float colbuf[D];
  const int t = threadIdx.x;
  const int c = t & 255;
  const int rb = t >> 8;
  const int r0 = rb * 32;
  float aug[32];
#pragma unroll
  for (int rr = 0; rr < 32; ++rr) {
    const int r = r0 + rr;
    aug[rr] = (c < D) ? Mm[r * D + c] : ((c - D == r) ? 1.f : 0.f);
  }
  for (int k = 0; k < D; ++k) {
    float rv = 0.f;
#pragma unroll
    for (int rr = 0; rr < 32; ++rr)
      if (rr == (k & 31)) rv = aug[rr];
    if (rb == (k >> 5)) rowbuf[c] = rv;
    if (c == k) {
#pragma unroll
      for (int rr = 0; rr < 32; ++rr) colbuf[r0 + rr] = aug[rr];
    }
    __syncthreads();
    const float invp = 1.f / rowbuf[k];
    const float pr = rowbuf[c] * invp;
#pragma unroll
    for (int rr = 0; rr < 32; ++rr) {
      const int r = r0 + rr;
      aug[rr] = (r == k) ? pr : fmaf(-colbuf[r], pr, aug[rr]);
    }
    __syncthreads();
  }
  if (c >= D) {
#pragma unroll
    for (int rr = 0; rr < 32; ++rr) Winv[(r0 + rr) * D + (c - D)] = aug[rr];
  }
}

// ---------------------------------------------------------------------------
// Kernel 3: fp16-split MFMA Peaceman-Rachford.
// Block = 256 thr (4 waves), 64 rows/wave, grid 256, 1 block/CU.
// Register plan (per wave): u12 state 128 VGPR; fragment transients ~32;
// acc 128 AGPR; bwAcc (bias@Winv^T) 128 AGPR carried as MFMA C-operand of
// the first MFMA of each tile -> no VALU bw add, no bw registers, no BW LDS.
// Arch-VGPR demand ~190 < 256: kills the round-3/4 scratch spills.
// ---------------------------------------------------------------------------
__global__ __launch_bounds__(256, 1) void mon_main(
    const float* __restrict__ x, const float* __restrict__ Uw,
    const float* __restrict__ ub, const float* __restrict__ Wg,
    const float* __restrict__ Winvg, float* __restrict__ out) {

  __shared__ u32x4 AH[2048];   // 32 KB hi f16, [row][16 granules], XOR swizzle
  __shared__ u32x4 AL[2048];   // 32 KB lo f16
  __shared__ float UB[D];

  const int t = threadIdx.x;
  const int w = t >> 6;
  const int l = t & 63;
  const int l5 = l & 31;
  const int hi5 = l >> 5;
  const int rg0 = blockIdx.x * 256 + w * 64 + l5;  // colset0 row
  const int rg1 = rg0 + 32;                        // colset1 row

  const int base_g = l5 * 16 + (hi5 ^ (l5 & 7));   // swizzled A granule base
  const int vub = hi5 * 16;
  const float* xr0 = x + (size_t)rg0 * D + hi5 * 8;
  const float* xr1 = x + (size_t)rg1 * D + hi5 * 8;

  f32x16 acc[2][4];
  f32x16 bwAcc[2][4];    // bias @ Winv^T, lives in AGPRs as MFMA C-source
  float u12[2][4][16];   // PR state per colset (also bias / z / aw)

  auto stageAB = [&](const float* __restrict__ M) {
#pragma unroll
    for (int it = 0; it < 8; ++it) {
      const int G = t + it * 256;
      const int i = G >> 4, g = G & 15;
      const float* src = M + i * D + g * 8;
      f32x4 a = *(const f32x4*)src;
      f32x4 b = *(const f32x4*)(src + 4);
      unsigned h0, l0_, h1, l1_, h2_, l2_, h3, l3_;
      split2(a[0], a[1], h0, l0_);
      split2(a[2], a[3], h1, l1_);
      split2(b[0], b[1], h2_, l2_);
      split2(b[2], b[3], h3, l3_);
      const int pg = g ^ (i & 7);
      AH[i * 16 + pg] = (u32x4){h0, h1, h2_, h3};
      AL[i * 16 + pg] = (u32x4){l0_, l1_, l2_, l3_};
    }
  };

  // acc[c] = A_staged @ (u12[c])^T (+ bwAcc[c] if useBw), 3-term fp16 split
  auto mfma_pass = [&](bool useBw) {
#pragma unroll
    for (int h2 = 0; h2 < 2; ++h2) {
#pragma unroll
      for (int ktl = 0; ktl < 4; ++ktl) {
        const int kt = 4 * h2 + ktl;
        const int jt = 2 * h2 + (ktl >> 1);
        const int eb = 8 * (ktl & 1);
        u32x4 fH[2], fL[2];
#pragma unroll
        for (int c = 0; c < 2; ++c) {
          unsigned oh[4], ol[4];
#pragma unroll
          for (int q = 0; q < 4; ++q)
            split2(u12[c][jt][eb + 2 * q], u12[c][jt][eb + 2 * q + 1], oh[q], ol[q]);
#pragma unroll
          for (int b = 0; b < 2; ++b) {
            auto rh = __builtin_amdgcn_permlane32_swap(oh[b], oh[2 + b], false, false);
            auto rl = __builtin_amdgcn_permlane32_swap(ol[b], ol[2 + b], false, false);
            fH[c][b] = rh[0]; fH[c][2 + b] = rh[1];
            fL[c][b] = rl[0]; fL[c][2 + b] = rl[1];
          }
        }
        const int gx = base_g ^ (2 * kt);
#pragma unroll
        for (int ft = 0; ft < 4; ++ft) {
          const u32x4 ah = AH[ft * 512 + gx];
          const u32x4 al = AL[ft * 512 + gx];
#pragma unroll
          for (int c = 0; c < 2; ++c) {
            if (kt == 0)
              acc[c][ft] = mm(ah, fH[c], useBw ? bwAcc[c][ft] : zero16());
            else
              acc[c][ft] = mm(ah, fH[c], acc[c][ft]);
            acc[c][ft] = mm(ah, fL[c], acc[c][ft]);
            acc[c][ft] = mm(al, fH[c], acc[c][ft]);
          }
        }
      }
    }
  };

  // acc[c] = x_rows(c) @ A_staged^T  (B-frags straight from global x)
  auto x_pass = [&](int c, const float* __restrict__ xrc) {
#pragma unroll
    for (int kt = 0; kt < 8; ++kt) {
      f32x4 xa = *(const f32x4*)(xrc + kt * 16);
      f32x4 xb = *(const f32x4*)(xrc + kt * 16 + 4);
      unsigned h0, l0_, h1, l1_, h2_, l2_, h3, l3_;
      split2(xa[0], xa[1], h0, l0_);
      split2(xa[2], xa[3], h1, l1_);
      split2(xb[0], xb[1], h2_, l2_);
      split2(xb[2], xb[3], h3, l3_);
      u32x4 fh = (u32x4){h0, h1, h2_, h3};
      u32x4 fl = (u32x4){l0_, l1_, l2_, l3_};
      const int gx = base_g ^ (2 * kt);
#pragma unroll
      for (int ft = 0; ft < 4; ++ft) {
        const u32x4 ah = AH[ft * 512 + gx];
        const u32x4 al = AL[ft * 512 + gx];
        acc[c][ft] = mm(ah, fh, kt == 0 ? zero16() : acc[c][ft]);
        acc[c][ft] = mm(ah, fl, acc[c][ft]);
        acc[c][ft] = mm(al, fh, acc[c][ft]);
      }
    }
  };

  // ---- Phase A: bias = x @ Uw^T + ub  (into u12)
  stageAB(Uw);
  if (t < D) UB[t] = ub[t];
  __syncthreads();
  x_pass(0, xr0);
  x_pass(1, xr1);
#pragma unroll
  for (int c = 0; c < 2; ++c)
#pragma unroll
    for (int ft = 0; ft < 4; ++ft)
#pragma unroll
      for (int e2 = 0; e2 < 8; ++e2) {
        const int i0 = 32 * ft + 2 * (e2 & 1) + 8 * (e2 >> 1);
        f32x2 ubp = *(const f32x2*)((const char*)UB + vub + 4 * i0);
        u12[c][ft][2 * e2] = acc[c][ft][2 * e2] + ubp[0];
        u12[c][ft][2 * e2 + 1] = acc[c][ft][2 * e2 + 1] + ubp[1];
      }
  __syncthreads();
  stageAB(Winvg);
  __syncthreads();

  // ---- Phase A2 (= PR iteration 1, u12_1 = 0): bw = bias @ Winv^T
  mfma_pass(false);  // reads u12 (= bias) -> acc = bw
#pragma unroll
  for (int c = 0; c < 2; ++c)
#pragma unroll
    for (int ft = 0; ft < 4; ++ft) {
      bwAcc[c][ft] = acc[c][ft];
#pragma unroll
      for (int e = 0; e < 16; ++e)
        u12[c][ft][e] = __builtin_fabsf(2.f * acc[c][ft][e]);
    }

  // ---- PR iterations 2..49 (48 full steps, no barriers)
#pragma unroll 1
  for (int it = 0; it < 48; ++it) {
    mfma_pass(true);  // acc = Winv @ u12 + bw
#pragma unroll
    for (int c = 0; c < 2; ++c)
#pragma unroll
      for (int ft = 0; ft < 4; ++ft)
#pragma unroll
        for (int e = 0; e < 16; ++e) {
          float t0 = 2.f * acc[c][ft][e] - u12[c][ft][e];
          u12[c][ft][e] = __builtin_fabsf(t0);
        }
  }

  // ---- Iteration 50: z = relu(2*z12 - u12)
  mfma_pass(true);
#pragma unroll
  for (int c = 0; c < 2; ++c)
#pragma unroll
    for (int ft = 0; ft < 4; ++ft)
#pragma unroll
      for (int e = 0; e < 16; ++e) {
        float t0 = 2.f * acc[c][ft][e] - u12[c][ft][e];
        u12[c][ft][e] = fmaxf(t0, 0.f);
      }

  // ---- Phase C1: aw = z @ W^T
  __syncthreads();
  stageAB(Wg);
  __syncthreads();
  mfma_pass(false);  // reads u12 (= z) -> acc = z @ W^T
#pragma unroll
  for (int c = 0; c < 2; ++c)
#pragma unroll
    for (int ft = 0; ft < 4; ++ft)
#pragma unroll
      for (int e = 0; e < 16; ++e) u12[c][ft][e] = acc[c][ft][e];  // keep aw

  // ---- Phase C2: out = relu(x@Uw^T + ub + aw)
  __syncthreads();
  stageAB(Uw);
  __syncthreads();
  x_pass(0, xr0);
  x_pass(1, xr1);
  float* op0 = out + (size_t)rg0 * D;
  float* op1 = out + (size_t)rg1 * D;
#pragma unroll
  for (int c = 0; c < 2; ++c) {
    float* op = c ? op1 : op0;
#pragma unroll
    for (int ft = 0; ft < 4; ++ft)
#pragma unroll
      for (int e2 = 0; e2 < 8; ++e2) {
        const int i0 = 32 * ft + 2 * (e2 & 1) + 8 * (e2 >> 1);
        f32x2 ubp = *(const f32x2*)((const char*)UB + vub + 4 * i0);
        float o0 = fmaxf(acc[c][ft][2 * e2] + ubp[0] + u12[c][ft][2 * e2], 0.f);
        float o1 = fmaxf(acc[c][ft][2 * e2 + 1] + ubp[1] + u12[c][ft][2 * e2 + 1], 0.f);
        *(f32x2*)(op + i0 + 4 * hi5) = (f32x2){o0, o1};
      }
  }
}

// ---------------------------------------------------------------------------
extern "C" void kernel_launch(void* const* d_in, const int* in_sizes, int n_in,
                              void* d_out, int out_size, void* d_ws, size_t ws_size,
                              hipStream_t stream) {
  const float* x = (const float*)d_in[0];
  const float* Uw = (const float*)d_in[1];
  const float* ub = (const float*)d_in[2];
  const float* A = (const float*)d_in[3];
  const float* B = (const float*)d_in[4];
  float* out = (float*)d_out;

  float* W = (float*)d_ws;        // 64 KB
  float* Mm = W + D * D;          // 64 KB
  float* Winv = W + 2 * D * D;    // 64 KB

  wmat_kernel<<<D, D, 0, stream>>>(A, B, W, Mm);
  inv_kernel<<<1, 1024, 0, stream>>>(Mm, Winv);

  const int batch = in_sizes[0] / D;  // 65536
  mon_main<<<batch / 256, 256, 0, stream>>>(x, Uw, ub, W, Winv, out);
}

// Round 6
// 641.699 us; speedup vs baseline: 1.2222x; 1.2222x over previous
//
#include <hip/hip_runtime.h>

#define D 128

typedef __attribute__((ext_vector_type(2))) float f32x2;
typedef __attribute__((ext_vector_type(4))) float f32x4;
typedef __attribute__((ext_vector_type(16))) float f32x16;
typedef __attribute__((ext_vector_type(8))) _Float16 f16x8;
typedef __attribute__((ext_vector_type(2))) __fp16 fp16v2;
typedef __attribute__((ext_vector_type(4))) unsigned int u32x4;

// split f32 pair -> packed f16 hi-pair + lo-pair
__device__ __forceinline__ void split2(float a, float b, unsigned &hi, unsigned &lo) {
  fp16v2 h = __builtin_amdgcn_cvt_pkrtz(a, b);
  float ra = a - (float)h[0];
  float rb = b - (float)h[1];
  fp16v2 lv = __builtin_amdgcn_cvt_pkrtz(ra, rb);
  hi = __builtin_bit_cast(unsigned, h);
  lo = __builtin_bit_cast(unsigned, lv);
}

__device__ __forceinline__ f32x16 mm(u32x4 a, u32x4 b, f32x16 c) {
  return __builtin_amdgcn_mfma_f32_32x32x16_f16(
      __builtin_bit_cast(f16x8, a), __builtin_bit_cast(f16x8, b), c, 0, 0, 0);
}

__device__ __forceinline__ f32x16 zero16() {
  f32x16 z;
#pragma unroll
  for (int e = 0; e < 16; ++e) z[e] = 0.f;
  return z;
}

// ---------------------------------------------------------------------------
// Kernel 1: W = 0.95 I - A^T A + B - B^T ;  Mm = 2 I - W
// ---------------------------------------------------------------------------
__global__ void wmat_kernel(const float* __restrict__ A, const float* __restrict__ B,
                            float* __restrict__ W, float* __restrict__ Mm) {
  const int i = blockIdx.x;
  const int j = threadIdx.x;
  float s = 0.f;
#pragma unroll 8
  for (int k = 0; k < D; ++k) s = fmaf(A[k * D + i], A[k * D + j], s);
  const float diag = (i == j) ? 1.f : 0.f;
  const float w = 0.95f * diag - s + B[i * D + j] - B[j * D + i];
  W[i * D + j] = w;
  Mm[i * D + j] = 2.f * diag - w;
}

// ---------------------------------------------------------------------------
// Kernel 2: Winv = Mm^{-1}, register-resident Gauss-Jordan (no pivoting).
// R6: f32x4 colbuf reads (8 ds insts, not 32) + double-buffered publish ->
// single barrier per step.
// ---------------------------------------------------------------------------
__global__ __launch_bounds__(1024) void inv_kernel(const float* __restrict__ Mm,
                                                   float* __restrict__ Winv) {
  __shared__ float rowbuf[2][2 * D];
  __shared__ __align__(16) float colbuf[2][D];
  const int t = threadIdx.x;
  const int c = t & 255;
  const int rb = t >> 8;
  const int r0 = rb * 32;
  float aug[32];
#pragma unroll
  for (int rr = 0; rr < 32; ++rr) {
    const int r = r0 + rr;
    aug[rr] = (c < D) ? Mm[r * D + c] : ((c - D == r) ? 1.f : 0.f);
  }
  // publish pivot 0 into buffer 0
  if (rb == 0) rowbuf[0][c] = aug[0];
  if (c == 0) {
#pragma unroll
    for (int rr = 0; rr < 32; ++rr) colbuf[0][r0 + rr] = aug[rr];
  }
  __syncthreads();
  for (int k = 0; k < D; ++k) {
    const int p = k & 1;
    const float invp = 1.f / rowbuf[p][k];
    const float pr = rowbuf[p][c] * invp;  // scaled pivot-row entry, my column
    float cb[32];
#pragma unroll
    for (int q = 0; q < 8; ++q) {
      f32x4 v = *(const f32x4*)&colbuf[p][r0 + 4 * q];
      cb[4 * q] = v[0]; cb[4 * q + 1] = v[1];
      cb[4 * q + 2] = v[2]; cb[4 * q + 3] = v[3];
    }
#pragma unroll
    for (int rr = 0; rr < 32; ++rr) {
      const int r = r0 + rr;
      aug[rr] = (r == k) ? pr : fmaf(-cb[rr], pr, aug[rr]);
    }
    if (k + 1 < D) {  // publish pivot k+1 (post-update) into buffer p^1
      float rv = 0.f;
#pragma unroll
      for (int rr = 0; rr < 32; ++rr)
        if (rr == ((k + 1) & 31)) rv = aug[rr];
      if (rb == ((k + 1) >> 5)) rowbuf[p ^ 1][c] = rv;
      if (c == k + 1) {
#pragma unroll
        for (int rr = 0; rr < 32; ++rr) colbuf[p ^ 1][r0 + rr] = aug[rr];
      }
    }
    __syncthreads();
  }
  if (c >= D) {
#pragma unroll
    for (int rr = 0; rr < 32; ++rr) Winv[(r0 + rr) * D + (c - D)] = aug[rr];
  }
}

// ---------------------------------------------------------------------------
// Kernel 3: fp16-split MFMA Peaceman-Rachford.
// Block = 256 thr (4 waves), 64 rows/wave, grid 256, 1 block/CU, 1 wave/SIMD.
// R6: acc + bwAcc force-homed into AGPRs via empty-asm "+a" pins (gfx950
// unified RF: without the pin LLVM keeps everything in the 256 arch VGPRs and
// spills ~125 regs/iter to scratch -> the R4/R5 1.6 GB FETCH).
// Arch class: u12 128 + transients ~80.  AGPR class: acc 128 + bwAcc 128.
// ---------------------------------------------------------------------------
__global__ __launch_bounds__(256, 1) void mon_main(
    const float* __restrict__ x, const float* __restrict__ Uw,
    const float* __restrict__ ub, const float* __restrict__ Wg,
    const float* __restrict__ Winvg, float* __restrict__ out) {

  __shared__ u32x4 AH[2048];   // 32 KB hi f16, [row][16 granules], XOR swizzle
  __shared__ u32x4 AL[2048];   // 32 KB lo f16
  __shared__ float UB[D];

  const int t = threadIdx.x;
  const int w = t >> 6;
  const int l = t & 63;
  const int l5 = l & 31;
  const int hi5 = l >> 5;
  const int rg0 = blockIdx.x * 256 + w * 64 + l5;  // colset0 row
  const int rg1 = rg0 + 32;                        // colset1 row

  const int base_g = l5 * 16 + (hi5 ^ (l5 & 7));   // swizzled A granule base
  const int vub = hi5 * 16;
  const float* xr0 = x + (size_t)rg0 * D + hi5 * 8;
  const float* xr1 = x + (size_t)rg1 * D + hi5 * 8;

  f32x16 acc[2][4];
  f32x16 bwAcc[2][4];    // bias @ Winv^T, AGPR-resident MFMA C-source
  float u12[2][4][16];   // PR state per colset (also bias / z / aw)

  auto pin_acc = [&]() {
#pragma unroll
    for (int c = 0; c < 2; ++c)
#pragma unroll
      for (int ft = 0; ft < 4; ++ft) asm("" : "+a"(acc[c][ft]));
  };
  auto pin_bw = [&]() {
#pragma unroll
    for (int c = 0; c < 2; ++c)
#pragma unroll
      for (int ft = 0; ft < 4; ++ft) asm("" : "+a"(bwAcc[c][ft]));
  };

  auto stageAB = [&](const float* __restrict__ M) {
#pragma unroll
    for (int it = 0; it < 8; ++it) {
      const int G = t + it * 256;
      const int i = G >> 4, g = G & 15;
      const float* src = M + i * D + g * 8;
      f32x4 a = *(const f32x4*)src;
      f32x4 b = *(const f32x4*)(src + 4);
      unsigned h0, l0_, h1, l1_, h2_, l2_, h3, l3_;
      split2(a[0], a[1], h0, l0_);
      split2(a[2], a[3], h1, l1_);
      split2(b[0], b[1], h2_, l2_);
      split2(b[2], b[3], h3, l3_);
      const int pg = g ^ (i & 7);
      AH[i * 16 + pg] = (u32x4){h0, h1, h2_, h3};
      AL[i * 16 + pg] = (u32x4){l0_, l1_, l2_, l3_};
    }
  };

  // acc[c] = A_staged @ (u12[c])^T (+ bwAcc[c] if useBw), 3-term fp16 split
  auto mfma_pass = [&](bool useBw) {
#pragma unroll
    for (int h2 = 0; h2 < 2; ++h2) {
#pragma unroll
      for (int ktl = 0; ktl < 4; ++ktl) {
        const int kt = 4 * h2 + ktl;
        const int jt = 2 * h2 + (ktl >> 1);
        const int eb = 8 * (ktl & 1);
        u32x4 fH[2], fL[2];
#pragma unroll
        for (int c = 0; c < 2; ++c) {
          unsigned oh[4], ol[4];
#pragma unroll
          for (int q = 0; q < 4; ++q)
            split2(u12[c][jt][eb + 2 * q], u12[c][jt][eb + 2 * q + 1], oh[q], ol[q]);
#pragma unroll
          for (int b = 0; b < 2; ++b) {
            auto rh = __builtin_amdgcn_permlane32_swap(oh[b], oh[2 + b], false, false);
            auto rl = __builtin_amdgcn_permlane32_swap(ol[b], ol[2 + b], false, false);
            fH[c][b] = rh[0]; fH[c][2 + b] = rh[1];
            fL[c][b] = rl[0]; fL[c][2 + b] = rl[1];
          }
        }
        const int gx = base_g ^ (2 * kt);
#pragma unroll
        for (int ft = 0; ft < 4; ++ft) {
          const u32x4 ah = AH[ft * 512 + gx];
          const u32x4 al = AL[ft * 512 + gx];
#pragma unroll
          for (int c = 0; c < 2; ++c) {
            if (kt == 0)
              acc[c][ft] = mm(ah, fH[c], useBw ? bwAcc[c][ft] : zero16());
            else
              acc[c][ft] = mm(ah, fH[c], acc[c][ft]);
            acc[c][ft] = mm(ah, fL[c], acc[c][ft]);
            acc[c][ft] = mm(al, fH[c], acc[c][ft]);
          }
        }
      }
    }
    pin_acc();
  };

  // acc[c] = x_rows(c) @ A_staged^T  (B-frags straight from global x)
  auto x_pass = [&](int c, const float* __restrict__ xrc) {
#pragma unroll
    for (int kt = 0; kt < 8; ++kt) {
      f32x4 xa = *(const f32x4*)(xrc + kt * 16);
      f32x4 xb = *(const f32x4*)(xrc + kt * 16 + 4);
      unsigned h0, l0_, h1, l1_, h2_, l2_, h3, l3_;
      split2(xa[0], xa[1], h0, l0_);
      split2(xa[2], xa[3], h1, l1_);
      split2(xb[0], xb[1], h2_, l2_);
      split2(xb[2], xb[3], h3, l3_);
      u32x4 fh = (u32x4){h0, h1, h2_, h3};
      u32x4 fl = (u32x4){l0_, l1_, l2_, l3_};
      const int gx = base_g ^ (2 * kt);
#pragma unroll
      for (int ft = 0; ft < 4; ++ft) {
        const u32x4 ah = AH[ft * 512 + gx];
        const u32x4 al = AL[ft * 512 + gx];
        acc[c][ft] = mm(ah, fh, kt == 0 ? zero16() : acc[c][ft]);
        acc[c][ft] = mm(ah, fl, acc[c][ft]);
        acc[c][ft] = mm(al, fh, acc[c][ft]);
      }
    }
  };

  // ---- Phase A: bias = x @ Uw^T + ub  (into u12)
  stageAB(Uw);
  if (t < D) UB[t] = ub[t];
  __syncthreads();
  x_pass(0, xr0);
  x_pass(1, xr1);
  pin_acc();
#pragma unroll
  for (int c = 0; c < 2; ++c)
#pragma unroll
    for (int ft = 0; ft < 4; ++ft)
#pragma unroll
      for (int e2 = 0; e2 < 8; ++e2) {
        const int i0 = 32 * ft + 2 * (e2 & 1) + 8 * (e2 >> 1);
        f32x2 ubp = *(const f32x2*)((const char*)UB + vub + 4 * i0);
        u12[c][ft][2 * e2] = acc[c][ft][2 * e2] + ubp[0];
        u12[c][ft][2 * e2 + 1] = acc[c][ft][2 * e2 + 1] + ubp[1];
      }
  __syncthreads();
  stageAB(Winvg);
  __syncthreads();

  // ---- Phase A2 (= PR iteration 1, u12_1 = 0): bw = bias @ Winv^T
  mfma_pass(false);  // reads u12 (= bias) -> acc = bw
#pragma unroll
  for (int c = 0; c < 2; ++c)
#pragma unroll
    for (int ft = 0; ft < 4; ++ft) {
      bwAcc[c][ft] = acc[c][ft];
#pragma unroll
      for (int e = 0; e < 16; ++e)
        u12[c][ft][e] = __builtin_fabsf(2.f * acc[c][ft][e]);
    }
  pin_bw();

  // ---- PR iterations 2..49 (48 full steps, no barriers)
#pragma unroll 1
  for (int it = 0; it < 48; ++it) {
    mfma_pass(true);  // acc = Winv @ u12 + bw
#pragma unroll
    for (int c = 0; c < 2; ++c)
#pragma unroll
      for (int ft = 0; ft < 4; ++ft)
#pragma unroll
        for (int e = 0; e < 16; ++e) {
          float t0 = 2.f * acc[c][ft][e] - u12[c][ft][e];
          u12[c][ft][e] = __builtin_fabsf(t0);
        }
  }

  // ---- Iteration 50: z = relu(2*z12 - u12)
  mfma_pass(true);
#pragma unroll
  for (int c = 0; c < 2; ++c)
#pragma unroll
    for (int ft = 0; ft < 4; ++ft)
#pragma unroll
      for (int e = 0; e < 16; ++e) {
        float t0 = 2.f * acc[c][ft][e] - u12[c][ft][e];
        u12[c][ft][e] = fmaxf(t0, 0.f);
      }

  // ---- Phase C1: aw = z @ W^T
  __syncthreads();
  stageAB(Wg);
  __syncthreads();
  mfma_pass(false);  // reads u12 (= z) -> acc = z @ W^T
#pragma unroll
  for (int c = 0; c < 2; ++c)
#pragma unroll
    for (int ft = 0; ft < 4; ++ft)
#pragma unroll
      for (int e = 0; e < 16; ++e) u12[c][ft][e] = acc[c][ft][e];  // keep aw

  // ---- Phase C2: out = relu(x@Uw^T + ub + aw)
  __syncthreads();
  stageAB(Uw);
  __syncthreads();
  x_pass(0, xr0);
  x_pass(1, xr1);
  pin_acc();
  float* op0 = out + (size_t)rg0 * D;
  float* op1 = out + (size_t)rg1 * D;
#pragma unroll
  for (int c = 0; c < 2; ++c) {
    float* op = c ? op1 : op0;
#pragma unroll
    for (int ft = 0; ft < 4; ++ft)
#pragma unroll
      for (int e2 = 0; e2 < 8; ++e2) {
        const int i0 = 32 * ft + 2 * (e2 & 1) + 8 * (e2 >> 1);
        f32x2 ubp = *(const f32x2*)((const char*)UB + vub + 4 * i0);
        float o0 = fmaxf(acc[c][ft][2 * e2] + ubp[0] + u12[c][ft][2 * e2], 0.f);
        float o1 = fmaxf(acc[c][ft][2 * e2 + 1] + ubp[1] + u12[c][ft][2 * e2 + 1], 0.f);
        *(f32x2*)(op + i0 + 4 * hi5) = (f32x2){o0, o1};
      }
  }
}

// ---------------------------------------------------------------------------
extern "C" void kernel_launch(void* const* d_in, const int* in_sizes, int n_in,
                              void* d_out, int out_size, void* d_ws, size_t ws_size,
                              hipStream_t stream) {
  const float* x = (const float*)d_in[0];
  const float* Uw = (const float*)d_in[1];
  const float* ub = (const float*)d_in[2];
  const float* A = (const float*)d_in[3];
  const float* B = (const float*)d_in[4];
  float* out = (float*)d_out;

  float* W = (float*)d_ws;        // 64 KB
  float* Mm = W + D * D;          // 64 KB
  float* Winv = W + 2 * D * D;    // 64 KB

  wmat_kernel<<<D, D, 0, stream>>>(A, B, W, Mm);
  inv_kernel<<<1, 1024, 0, stream>>>(Mm, Winv);

  const int batch = in_sizes[0] / D;  // 65536
  mon_main<<<batch / 256, 256, 0, stream>>>(x, Uw, ub, W, Winv, out);
}